// Round 9
// baseline (338.387 us; speedup 1.0000x reference)
//
#include <hip/hip_runtime.h>
#include <hip/hip_bf16.h>

typedef short bf16x8 __attribute__((ext_vector_type(8)));
typedef float f32x4 __attribute__((ext_vector_type(4)));
typedef unsigned short ushort8v __attribute__((ext_vector_type(8)));

#define SBAR() asm volatile("s_barrier" ::: "memory")
#define LGKM0() do { asm volatile("s_waitcnt lgkmcnt(0)" ::: "memory"); \
    __builtin_amdgcn_sched_barrier(0); } while (0)

__device__ __forceinline__ unsigned short f2bf(float f) {
  unsigned u = __builtin_bit_cast(unsigned, f);
  u += 0x7fffu + ((u >> 16) & 1u);   // round-to-nearest-even
  return (unsigned short)(u >> 16);
}

__device__ __forceinline__ void gload_lds16(const unsigned short* g, unsigned short* l) {
  __builtin_amdgcn_global_load_lds((const __attribute__((address_space(1))) void*)g,
                                   (__attribute__((address_space(3))) void*)l, 16, 0, 0);
}

// ---------------- fused prep: xb = bf16(x); wb = bf16(W + scale*B@A) ----------------
__global__ __launch_bounds__(256) void prep_kernel(const float* __restrict__ x,
                                                   const float* __restrict__ W,
                                                   const float* __restrict__ A,
                                                   const float* __restrict__ Bm,
                                                   unsigned short* __restrict__ xb,
                                                   unsigned short* __restrict__ wb,
                                                   float scale, int K, int R, int n8, int t8) {
  int i = blockIdx.x * 256 + threadIdx.x;
  if (i < n8) {
    const float4* p = (const float4*)x + (size_t)i * 2;
    float4 a = p[0], b = p[1];
    ushort8v v;
    v[0] = f2bf(a.x); v[1] = f2bf(a.y); v[2] = f2bf(a.z); v[3] = f2bf(a.w);
    v[4] = f2bf(b.x); v[5] = f2bf(b.y); v[6] = f2bf(b.z); v[7] = f2bf(b.w);
    *((ushort8v*)xb + i) = v;
    return;
  }
  int idx = i - n8;
  if (idx >= t8) return;
  int perRow = K >> 3;
  int n = idx / perRow;
  int d0 = (idx - n * perRow) << 3;
  const float4* wp = (const float4*)(W + (size_t)n * K + d0);
  float4 w0 = wp[0], w1 = wp[1];
  float acc[8] = {w0.x, w0.y, w0.z, w0.w, w1.x, w1.y, w1.z, w1.w};
#pragma unroll 4
  for (int r = 0; r < R; ++r) {
    float c = Bm[(size_t)n * R + r] * scale;
    const float4* ap = (const float4*)(A + (size_t)r * K + d0);
    float4 a0 = ap[0], a1 = ap[1];
    acc[0] += c * a0.x; acc[1] += c * a0.y; acc[2] += c * a0.z; acc[3] += c * a0.w;
    acc[4] += c * a1.x; acc[5] += c * a1.y; acc[6] += c * a1.z; acc[7] += c * a1.w;
  }
  ushort8v v;
#pragma unroll
  for (int j = 0; j < 8; ++j) v[j] = f2bf(acc[j]);
  *((ushort8v*)wb + idx) = v;
}

// ---------------- 256x256 8-phase bf16 GEMM, hoisted addressing ----------------
// BK=64, 8 waves (2Mx4N, wave 128x64), 2 LDS buffers (2x64KB), manual 2x unroll
// (compile-time buffer parity) -> all 24 ds_reads are base-ptr + imm-offset.
// Staging for tile c+1 during step c: B sites 0-3 @P1/P2, A sites {0,2} @P3,
// A sites {1,3} @P4. Certify: vmcnt(4)@P2 (A13(c), aged 3 phases),
// vmcnt(2)@P4 (B+A02(c+1), aged 2-3 phases). Never drain in main loop.
// Buffer (bytes): A[256][64] at [0,32768); B[256][64] at [32768,65536).
// Swizzle: 16B chunk c holds global chunk c ^ (row&7) (involution, both sides).
__global__ __launch_bounds__(512, 2) void gemm256_bt_bias(const unsigned short* __restrict__ Xb,
                                                          const unsigned short* __restrict__ Wb,
                                                          const float* __restrict__ bias,
                                                          float* __restrict__ C,
                                                          int M, int N, int K) {
  __shared__ __align__(16) char lds[131072];
  const int t = threadIdx.x;
  const int wave = t >> 6, lane = t & 63;
  const int fr = lane & 15, kc = lane >> 4;
  const int wr = wave >> 2, wc = wave & 3;

  const int NTn = N >> 8;
  const int nwg = gridDim.x;
  int bid = blockIdx.x;
  if ((nwg & 7) == 0) bid = (bid & 7) * (nwg >> 3) + (bid >> 3);  // XCD swizzle
  const int tm = bid / NTn, tn = bid % NTn;
  const int m0 = tm << 8, n0 = tn << 8;

  // ---- staging source (pre-swizzled global chunk), advancing pointers ----
  const int grow = t >> 3;
  const int gch8 = ((t & 7) ^ ((t >> 3) & 7)) << 3;
  const size_t K64 = (size_t)64 * K;
  const unsigned short* pa = Xb + (size_t)(m0 + grow) * K + gch8;  // tile 0
  const unsigned short* pb = Wb + (size_t)(n0 + grow) * K + gch8;
  char* const sb = (char*)lds + wave * 1024;  // wave-region staging dest base

  // ---- loop-invariant ds_read base pointers (imm offsets 0..14336) ----
  const int sw  = (lane & 7) << 4;
  const int cb0 = (kc << 4) ^ sw;
  const int cb1 = cb0 ^ 64;                   // ((4+kc)<<4)^sw == cb0^64 (kc<4)
  const int rowA = (wr * 128 + fr) * 128;
  const int rowB = 32768 + (wc * 64 + fr) * 128;
  const char* rA0[2] = { (char*)lds + rowA + cb0, (char*)lds + 65536 + rowA + cb0 };
  const char* rA1[2] = { (char*)lds + rowA + cb1, (char*)lds + 65536 + rowA + cb1 };
  const char* rB0[2] = { (char*)lds + rowB + cb0, (char*)lds + 65536 + rowB + cb0 };
  const char* rB1[2] = { (char*)lds + rowB + cb1, (char*)lds + 65536 + rowB + cb1 };

  f32x4 acc[8][4];
#pragma unroll
  for (int m = 0; m < 8; ++m)
#pragma unroll
    for (int n = 0; n < 4; ++n) acc[m][n] = (f32x4){0.f, 0.f, 0.f, 0.f};

  bf16x8 aQa[8], aQb[8], bQ0[4], bQ1[4];
  const int NT = K >> 6;   // even (K % 128 == 0 enforced by launcher)

#define STG_A1(BUF, s) gload_lds16(pa + (size_t)(s) * K64, \
    (unsigned short*)(sb + ((BUF) ? 65536 : 0) + (s) * 8192))
#define STG_B1(BUF, s) gload_lds16(pb + (size_t)(s) * K64, \
    (unsigned short*)(sb + ((BUF) ? 65536 : 0) + 32768 + (s) * 8192))

#define MM(qm, qn, AR, BR) do { \
    __builtin_amdgcn_s_setprio(1); \
    _Pragma("unroll") for (int ks = 0; ks < 2; ++ks) \
    _Pragma("unroll") for (int m = 0; m < 4; ++m) \
    _Pragma("unroll") for (int n = 0; n < 2; ++n) \
      acc[(qm)*4+m][(qn)*2+n] = __builtin_amdgcn_mfma_f32_16x16x32_bf16( \
          AR[m*2+ks], BR[n*2+ks], acc[(qm)*4+m][(qn)*2+n], 0, 0, 0); \
    __builtin_amdgcn_s_setprio(0); } while (0)

  // STEP consumes buffer BUF; stages tile c+1 into BUF^1 (if DOSTG).
#define STEP(BUF, DOSTG, VM2, VM4) do { \
    /* P1: Q(0,0) -- 12 ds_reads + 2 B-stages */ \
    aQa[0]=*(const bf16x8*)(rA0[BUF]);        aQa[1]=*(const bf16x8*)(rA1[BUF]); \
    aQa[2]=*(const bf16x8*)(rA0[BUF]+2048);   aQa[3]=*(const bf16x8*)(rA1[BUF]+2048); \
    aQa[4]=*(const bf16x8*)(rA0[BUF]+4096);   aQa[5]=*(const bf16x8*)(rA1[BUF]+4096); \
    aQa[6]=*(const bf16x8*)(rA0[BUF]+6144);   aQa[7]=*(const bf16x8*)(rA1[BUF]+6144); \
    bQ0[0]=*(const bf16x8*)(rB0[BUF]);        bQ0[1]=*(const bf16x8*)(rB1[BUF]); \
    bQ0[2]=*(const bf16x8*)(rB0[BUF]+2048);   bQ0[3]=*(const bf16x8*)(rB1[BUF]+2048); \
    if (DOSTG) { STG_B1(BUF^1, 0); STG_B1(BUF^1, 1); } \
    asm volatile("s_waitcnt lgkmcnt(8)" ::: "memory"); \
    SBAR(); LGKM0(); MM(0, 0, aQa, bQ0); SBAR(); \
    /* P2: Q(0,1) -- certify A13(c) with counted vmcnt */ \
    bQ1[0]=*(const bf16x8*)(rB0[BUF]+4096);   bQ1[1]=*(const bf16x8*)(rB1[BUF]+4096); \
    bQ1[2]=*(const bf16x8*)(rB0[BUF]+6144);   bQ1[3]=*(const bf16x8*)(rB1[BUF]+6144); \
    if (DOSTG) { STG_B1(BUF^1, 2); STG_B1(BUF^1, 3); } \
    asm volatile("s_waitcnt vmcnt(" VM2 ")" ::: "memory"); \
    SBAR(); LGKM0(); MM(0, 1, aQa, bQ1); SBAR(); \
    /* P3: Q(1,0) -- reads A sites {1,3} (certified at P2) */ \
    aQb[0]=*(const bf16x8*)(rA0[BUF]+8192);   aQb[1]=*(const bf16x8*)(rA1[BUF]+8192); \
    aQb[2]=*(const bf16x8*)(rA0[BUF]+10240);  aQb[3]=*(const bf16x8*)(rA1[BUF]+10240); \
    aQb[4]=*(const bf16x8*)(rA0[BUF]+12288);  aQb[5]=*(const bf16x8*)(rA1[BUF]+12288); \
    aQb[6]=*(const bf16x8*)(rA0[BUF]+14336);  aQb[7]=*(const bf16x8*)(rA1[BUF]+14336); \
    if (DOSTG) { STG_A1(BUF^1, 0); STG_A1(BUF^1, 2); } \
    SBAR(); LGKM0(); MM(1, 0, aQb, bQ0); SBAR(); \
    /* P4: Q(1,1) -- certify B+A02(c+1) with counted vmcnt */ \
    if (DOSTG) { STG_A1(BUF^1, 1); STG_A1(BUF^1, 3); pa += 64; pb += 64; } \
    asm volatile("s_waitcnt vmcnt(" VM4 ")" ::: "memory"); \
    SBAR(); MM(1, 1, aQb, bQ1); SBAR(); \
  } while (0)

  // prologue: stage tile 0 (B0-3, A0, A2, A1, A3); certify B+A02 (allow A13).
  STG_B1(0, 0); STG_B1(0, 1); STG_B1(0, 2); STG_B1(0, 3);
  STG_A1(0, 0); STG_A1(0, 2); STG_A1(0, 1); STG_A1(0, 3);
  pa += 64; pb += 64;
  asm volatile("s_waitcnt vmcnt(2)" ::: "memory");
  SBAR();

  for (int cc = 0; cc < NT - 2; cc += 2) {
    STEP(0, 1, "4", "2");
    STEP(1, 1, "4", "2");
  }
  STEP(0, 1, "4", "2");   // step NT-2 (even, buf0): stages tile NT-1
  STEP(1, 0, "0", "0");   // step NT-1 (buf1): no staging, drain A13

  // epilogue: D map col = lane&15, row = (lane>>4)*4 + reg
  const int crow = (lane >> 4) * 4;
  const int ccol = lane & 15;
#pragma unroll
  for (int n = 0; n < 4; ++n) {
    int col = n0 + wc * 64 + n * 16 + ccol;
    float bv = bias[col];
#pragma unroll
    for (int m = 0; m < 8; ++m) {
      int row = m0 + wr * 128 + m * 16 + crow;
      float* cp = C + (size_t)row * N + col;
#pragma unroll
      for (int r = 0; r < 4; ++r) cp[(size_t)r * N] = acc[m][n][r] + bv;
    }
  }
#undef STG_A1
#undef STG_B1
#undef MM
#undef STEP
}

// ---------------- 128x128 m97-structure fallback GEMM ----------------
__global__ __launch_bounds__(256) void gemm_bt_bias(const unsigned short* __restrict__ Xb,
                                                    const unsigned short* __restrict__ Wb,
                                                    const float* __restrict__ bias,
                                                    float* __restrict__ C,
                                                    int M, int N, int K) {
  __shared__ unsigned short sA[128 * 32];
  __shared__ unsigned short sB[128 * 32];
  const int t = threadIdx.x;
  const int wave = t >> 6, lane = t & 63;
  const int NT = N >> 7;
  const int nwg = gridDim.x;
  int bid = blockIdx.x;
  if ((nwg & 7) == 0) bid = (bid & 7) * (nwg >> 3) + (bid >> 3);
  const int tm = bid / NT, tn = bid % NT;
  const int m0 = tm << 7, n0 = tn << 7;
  const int wr = wave >> 1, wc = wave & 1;

  f32x4 acc[4][4];
#pragma unroll
  for (int m = 0; m < 4; ++m)
#pragma unroll
    for (int n = 0; n < 4; ++n) acc[m][n] = (f32x4){0.f, 0.f, 0.f, 0.f};

  const unsigned short* gA0 = Xb + (size_t)(m0 + (t >> 2)) * K + (t & 3) * 8;
  const unsigned short* gA1 = Xb + (size_t)(m0 + 64 + (t >> 2)) * K + (t & 3) * 8;
  const unsigned short* gB0 = Wb + (size_t)(n0 + (t >> 2)) * K + (t & 3) * 8;
  const unsigned short* gB1 = Wb + (size_t)(n0 + 64 + (t >> 2)) * K + (t & 3) * 8;
  unsigned short* lA0 = sA + (size_t)(wave * 64) * 8;
  unsigned short* lA1 = sA + (size_t)(256 + wave * 64) * 8;
  unsigned short* lB0 = sB + (size_t)(wave * 64) * 8;
  unsigned short* lB1 = sB + (size_t)(256 + wave * 64) * 8;

  const int rrow = lane & 15;
  const int rk = (lane >> 4) * 8;

  for (int k0 = 0; k0 < K; k0 += 32) {
    gload_lds16(gA0 + k0, lA0);
    gload_lds16(gA1 + k0, lA1);
    gload_lds16(gB0 + k0, lB0);
    gload_lds16(gB1 + k0, lB1);
    __syncthreads();
    bf16x8 af[4], bfr[4];
#pragma unroll
    for (int m = 0; m < 4; ++m)
      af[m] = *(const bf16x8*)&sA[(size_t)(wr * 64 + m * 16 + rrow) * 32 + rk];
#pragma unroll
    for (int n = 0; n < 4; ++n)
      bfr[n] = *(const bf16x8*)&sB[(size_t)(wc * 64 + n * 16 + rrow) * 32 + rk];
#pragma unroll
    for (int m = 0; m < 4; ++m)
#pragma unroll
      for (int n = 0; n < 4; ++n)
        acc[m][n] = __builtin_amdgcn_mfma_f32_16x16x32_bf16(af[m], bfr[n], acc[m][n], 0, 0, 0);
    __syncthreads();
  }
  const int crow0 = (lane >> 4) * 4;
  const int ccol = lane & 15;
#pragma unroll
  for (int n = 0; n < 4; ++n) {
    int col = n0 + wc * 64 + n * 16 + ccol;
    float bv = bias[col];
#pragma unroll
    for (int m = 0; m < 4; ++m) {
      int row = m0 + wr * 64 + m * 16 + crow0;
      float* cp = C + (size_t)row * N + col;
#pragma unroll
      for (int r = 0; r < 4; ++r) cp[(size_t)r * N] = acc[m][n][r] + bv;
    }
  }
}

// ---------------- fp32 fallback ----------------
__global__ __launch_bounds__(64) void lora_h_kernel(const float* __restrict__ x,
                                                    const float* __restrict__ A,
                                                    float* __restrict__ h,
                                                    float scale, int K, int R) {
  int m = blockIdx.x, lane = threadIdx.x;
  float acc[16];
#pragma unroll
  for (int r = 0; r < 16; ++r) acc[r] = 0.f;
  for (int d = lane; d < K; d += 64) {
    float xv = x[(size_t)m * K + d];
    for (int r = 0; r < R; ++r) acc[r] += xv * A[(size_t)r * K + d];
  }
  for (int off = 32; off; off >>= 1)
    for (int r = 0; r < R; ++r) acc[r] += __shfl_down(acc[r], off);
  if (lane == 0)
    for (int r = 0; r < R; ++r) h[(size_t)m * R + r] = acc[r] * scale;
}

__global__ __launch_bounds__(256) void fgemm_fallback(const float* __restrict__ X,
                                                      const float* __restrict__ W,
                                                      const float* __restrict__ Bm,
                                                      const float* __restrict__ bias,
                                                      const float* __restrict__ h,
                                                      float* __restrict__ C,
                                                      int M, int N, int K, int R) {
  __shared__ float sX[64][20];
  __shared__ float sW[64][20];
  int nt = N >> 6;
  int bx = blockIdx.x % nt, by = blockIdx.x / nt;
  int m0 = by << 6, n0 = bx << 6;
  int t = threadIdx.x;
  int tx = t & 15, ty = t >> 4;
  float acc[4][4] = {};
  int lr = t >> 2, lc = (t & 3) << 2;
  for (int k0 = 0; k0 < K; k0 += 16) {
    *(float4*)&sX[lr][lc] = *(const float4*)&X[(size_t)(m0 + lr) * K + k0 + lc];
    *(float4*)&sW[lr][lc] = *(const float4*)&W[(size_t)(n0 + lr) * K + k0 + lc];
    __syncthreads();
#pragma unroll
    for (int kk = 0; kk < 16; ++kk) {
      float a[4], b[4];
#pragma unroll
      for (int i = 0; i < 4; ++i) a[i] = sX[ty * 4 + i][kk];
#pragma unroll
      for (int j = 0; j < 4; ++j) b[j] = sW[tx * 4 + j][kk];
#pragma unroll
      for (int i = 0; i < 4; ++i)
#pragma unroll
        for (int j = 0; j < 4; ++j) acc[i][j] += a[i] * b[j];
    }
    __syncthreads();
  }
#pragma unroll
  for (int i = 0; i < 4; ++i) {
    int row = m0 + ty * 4 + i;
#pragma unroll
    for (int j = 0; j < 4; ++j) {
      int col = n0 + tx * 4 + j;
      float lo = 0.f;
      for (int r = 0; r < R; ++r) lo += h[(size_t)row * R + r] * Bm[(size_t)col * R + r];
      C[(size_t)row * N + col] = acc[i][j] + bias[col] + lo;
    }
  }
}

extern "C" void kernel_launch(void* const* d_in, const int* in_sizes, int n_in,
                              void* d_out, int out_size, void* d_ws, size_t ws_size,
                              hipStream_t stream) {
  const float* x    = (const float*)d_in[0];
  const float* W    = (const float*)d_in[1];
  const float* A    = (const float*)d_in[2];
  const float* Bm   = (const float*)d_in[3];
  const float* bias = (const float*)d_in[4];
  float* out = (float*)d_out;

  const int N = in_sizes[4];
  const int R = in_sizes[3] / N;
  const int K = in_sizes[2] / R;
  const int M = in_sizes[0] / K;
  const float scale = 16.0f / (float)R;

  const size_t xbytes = (size_t)M * K * 2;
  const size_t wbytes = (size_t)N * K * 2;
  const bool ws_ok = (ws_size >= xbytes + wbytes);
  const bool fast256 = ws_ok && (M % 256 == 0) && (N % 256 == 0) && (K % 128 == 0) && (K >= 256);
  const bool fast128 = ws_ok && (M % 128 == 0) && (N % 128 == 0) && (K % 32 == 0);

  if (fast256 || fast128) {
    unsigned short* xb = (unsigned short*)d_ws;
    unsigned short* wb = (unsigned short*)((char*)d_ws + xbytes);
    int n8 = M * K / 8;
    int t8 = N * K / 8;
    int total = n8 + t8;
    prep_kernel<<<dim3((total + 255) / 256), dim3(256), 0, stream>>>(x, W, A, Bm, xb, wb,
                                                                     scale, K, R, n8, t8);
    if (fast256) {
      int grid = (M / 256) * (N / 256);
      gemm256_bt_bias<<<dim3(grid), dim3(512), 0, stream>>>(xb, wb, bias, out, M, N, K);
    } else {
      int grid = (M / 128) * (N / 128);
      gemm_bt_bias<<<dim3(grid), dim3(256), 0, stream>>>(xb, wb, bias, out, M, N, K);
    }
  } else {
    float* h = (float*)d_ws;
    lora_h_kernel<<<dim3(M), dim3(64), 0, stream>>>(x, A, h, scale, K, R);
    int grid = (M / 64) * (N / 64);
    fgemm_fallback<<<dim3(grid), dim3(256), 0, stream>>>(x, W, Bm, bias, h, out, M, N, K, R);
  }
}